// Round 3
// baseline (652.864 us; speedup 1.0000x reference)
//
#include <hip/hip_runtime.h>
#include <math.h>

#define DM 128
#define DI 256
#define DSN 64
#define NB 8
#define LSEQ 4096
#define NTOK (NB*LSEQ)
#define XDBL_LD 136
#define GRP 8
#define GLEN (LSEQ/GRP)   // 512

typedef float4 f4;

__device__ __forceinline__ float sigmoidf_(float x){ return 1.f/(1.f+__expf(-x)); }
__device__ __forceinline__ float rdlane(float v, int j){
    return __int_as_float(__builtin_amdgcn_readlane(__float_as_int(v), j));
}

// ---------------- LayerNorm stats (mu, rstd) per token ----------------
__global__ void __launch_bounds__(256) k_lnstats(const float* __restrict__ x, float* __restrict__ stats){
    int tok = blockIdx.x*4 + (threadIdx.x>>6);
    int lane = threadIdx.x & 63;
    const float* row = x + (size_t)tok*DM;
    float a = row[lane], b = row[lane+64];
    float s = a+b, ss = a*a+b*b;
    #pragma unroll
    for (int off=32; off>0; off>>=1){ s += __shfl_xor(s,off); ss += __shfl_xor(ss,off); }
    if (lane==0){
        float mu = s*(1.f/128.f);
        float var = ss*(1.f/128.f) - mu*mu;
        stats[tok*2+0] = mu;
        stats[tok*2+1] = rsqrtf(var + 1e-6f);
    }
}

// ---------------- fp32 tiled GEMM: C[M][N] = A[M][K] * Bw[N][K]^T ----------------
template<int N_DIM,int K_DIM,int MODE>
__global__ void __launch_bounds__(256) k_gemm(const float* __restrict__ Asrc,
    const float* __restrict__ Bw, float* __restrict__ Cout, int ldC,
    const float* __restrict__ stats, const float* __restrict__ nw,
    const float* __restrict__ nb, const float* __restrict__ resid)
{
    __shared__ float As[32][68];
    __shared__ float Bs[32][68];
    const int tid = threadIdx.x;
    const int m0 = blockIdx.x*64;
    const int n0 = blockIdx.y*64;
    float acc[4][4] = {{0.f,0.f,0.f,0.f},{0.f,0.f,0.f,0.f},{0.f,0.f,0.f,0.f},{0.f,0.f,0.f,0.f}};
    const int tm = (tid & 15)*4;
    const int tn = (tid >> 4)*4;

    for (int k0=0; k0<K_DIM; k0+=32){
        if (MODE==2){
            int kk = tid>>3;
            int mm = (tid&7)*8;
            int bb = m0 >> 12;
            int t0 = m0 & (LSEQ-1);
            const float* src = Asrc + ((size_t)(bb*DI + k0 + kk))*LSEQ + t0 + mm;
            f4 v0 = *(const f4*)src, v1 = *(const f4*)(src+4);
            *(f4*)&As[kk][mm]   = v0;
            *(f4*)&As[kk][mm+4] = v1;
        } else {
            int mm = tid>>2;
            int kk = (tid&3)*8;
            int m = m0 + mm;
            const float* src = Asrc + (size_t)m*K_DIM + k0 + kk;
            f4 v0 = *(const f4*)src, v1 = *(const f4*)(src+4);
            if (MODE==0){
                float mu = stats[m*2+0], rs = stats[m*2+1];
                f4 w0 = *(const f4*)(nw+k0+kk), w1 = *(const f4*)(nw+k0+kk+4);
                f4 c0 = *(const f4*)(nb+k0+kk), c1 = *(const f4*)(nb+k0+kk+4);
                v0.x=(v0.x-mu)*rs*w0.x+c0.x; v0.y=(v0.y-mu)*rs*w0.y+c0.y;
                v0.z=(v0.z-mu)*rs*w0.z+c0.z; v0.w=(v0.w-mu)*rs*w0.w+c0.w;
                v1.x=(v1.x-mu)*rs*w1.x+c1.x; v1.y=(v1.y-mu)*rs*w1.y+c1.y;
                v1.z=(v1.z-mu)*rs*w1.z+c1.z; v1.w=(v1.w-mu)*rs*w1.w+c1.w;
            }
            As[kk+0][mm]=v0.x; As[kk+1][mm]=v0.y; As[kk+2][mm]=v0.z; As[kk+3][mm]=v0.w;
            As[kk+4][mm]=v1.x; As[kk+5][mm]=v1.y; As[kk+6][mm]=v1.z; As[kk+7][mm]=v1.w;
        }
        {
            int nn = tid>>2;
            int kk = (tid&3)*8;
            int n = n0 + nn;
            f4 v0 = {0.f,0.f,0.f,0.f}, v1 = {0.f,0.f,0.f,0.f};
            if (N_DIM%64==0 || n < N_DIM){
                const float* src = Bw + (size_t)n*K_DIM + k0 + kk;
                v0 = *(const f4*)src; v1 = *(const f4*)(src+4);
            }
            Bs[kk+0][nn]=v0.x; Bs[kk+1][nn]=v0.y; Bs[kk+2][nn]=v0.z; Bs[kk+3][nn]=v0.w;
            Bs[kk+4][nn]=v1.x; Bs[kk+5][nn]=v1.y; Bs[kk+6][nn]=v1.z; Bs[kk+7][nn]=v1.w;
        }
        __syncthreads();
        #pragma unroll
        for (int kk=0;kk<32;++kk){
            f4 av = *(const f4*)&As[kk][tm];
            f4 bv = *(const f4*)&Bs[kk][tn];
            acc[0][0]=fmaf(av.x,bv.x,acc[0][0]); acc[0][1]=fmaf(av.x,bv.y,acc[0][1]);
            acc[0][2]=fmaf(av.x,bv.z,acc[0][2]); acc[0][3]=fmaf(av.x,bv.w,acc[0][3]);
            acc[1][0]=fmaf(av.y,bv.x,acc[1][0]); acc[1][1]=fmaf(av.y,bv.y,acc[1][1]);
            acc[1][2]=fmaf(av.y,bv.z,acc[1][2]); acc[1][3]=fmaf(av.y,bv.w,acc[1][3]);
            acc[2][0]=fmaf(av.z,bv.x,acc[2][0]); acc[2][1]=fmaf(av.z,bv.y,acc[2][1]);
            acc[2][2]=fmaf(av.z,bv.z,acc[2][2]); acc[2][3]=fmaf(av.z,bv.w,acc[2][3]);
            acc[3][0]=fmaf(av.w,bv.x,acc[3][0]); acc[3][1]=fmaf(av.w,bv.y,acc[3][1]);
            acc[3][2]=fmaf(av.w,bv.z,acc[3][2]); acc[3][3]=fmaf(av.w,bv.w,acc[3][3]);
        }
        __syncthreads();
    }
    int n = n0 + tn;
    if (N_DIM%64==0 || n + 4 <= N_DIM){
        #pragma unroll
        for (int mi=0;mi<4;++mi){
            int m = m0+tm+mi;
            f4 v = {acc[mi][0],acc[mi][1],acc[mi][2],acc[mi][3]};
            if (MODE==2){
                f4 r = *(const f4*)(resid + (size_t)m*N_DIM + n);
                v.x+=r.x; v.y+=r.y; v.z+=r.z; v.w+=r.w;
            }
            *(f4*)(Cout + (size_t)m*ldC + n) = v;
        }
    }
}

// ---------------- causal depthwise conv (k=4) + SiLU ----------------
__global__ void __launch_bounds__(256) k_conv(const float* __restrict__ xz,
    const float* __restrict__ cw, const float* __restrict__ cb, float* __restrict__ u)
{
    int idx = blockIdx.x*256 + threadIdx.x;
    int dq = idx & 63;
    int tok = idx >> 6;
    int t = tok & (LSEQ-1);
    f4 w0 = *(const f4*)(cw + (dq*4+0)*4);
    f4 w1 = *(const f4*)(cw + (dq*4+1)*4);
    f4 w2 = *(const f4*)(cw + (dq*4+2)*4);
    f4 w3 = *(const f4*)(cw + (dq*4+3)*4);
    f4 r  = *(const f4*)(cb + dq*4);
    #pragma unroll
    for (int j=0;j<4;++j){
        int tj = t-3+j;
        if (tj < 0) continue;
        f4 v = *(const f4*)(xz + (size_t)(tok-3+j)*(2*DI) + dq*4);
        r.x = fmaf(v.x, ((const float*)&w0)[j], r.x);
        r.y = fmaf(v.y, ((const float*)&w1)[j], r.y);
        r.z = fmaf(v.z, ((const float*)&w2)[j], r.z);
        r.w = fmaf(v.w, ((const float*)&w3)[j], r.w);
    }
    r.x *= sigmoidf_(r.x); r.y *= sigmoidf_(r.y);
    r.z *= sigmoidf_(r.z); r.w *= sigmoidf_(r.w);
    *(f4*)(u + (size_t)tok*DI + dq*4) = r;
}

// ---------------- delta = softplus(dt @ Wdt^T + bdt) ----------------
__global__ void __launch_bounds__(256) k_delta(const float* __restrict__ xdbl,
    const float* __restrict__ Wdt, const float* __restrict__ bdt, float* __restrict__ delta)
{
    int d = threadIdx.x;
    int tok0 = blockIdx.x * 16;
    f4 w0 = *(const f4*)(Wdt + d*8);
    f4 w1 = *(const f4*)(Wdt + d*8 + 4);
    float bias = bdt[d];
    __shared__ float dts[16][8];
    if (threadIdx.x < 128){
        int ti = threadIdx.x >> 3, r = threadIdx.x & 7;
        dts[ti][r] = xdbl[(size_t)(tok0+ti)*XDBL_LD + r];
    }
    __syncthreads();
    #pragma unroll 4
    for (int ti=0; ti<16; ++ti){
        f4 d0 = *(const f4*)&dts[ti][0];
        f4 d1 = *(const f4*)&dts[ti][4];
        float v = bias;
        v = fmaf(d0.x,w0.x, v); v = fmaf(d0.y,w0.y, v);
        v = fmaf(d0.z,w0.z, v); v = fmaf(d0.w,w0.w, v);
        v = fmaf(d1.x,w1.x, v); v = fmaf(d1.y,w1.y, v);
        v = fmaf(d1.z,w1.z, v); v = fmaf(d1.w,w1.w, v);
        float sp = (v > 20.f) ? v : log1pf(__expf(v));
        delta[(size_t)(tok0+ti)*DI + d] = sp;
    }
}

// ---------------- scan pass 1: per-group (decay product, local final state) ----------------
// grid: 3584 blocks (XCD x owns batch b=x); block = 4 waves = 4 consecutive d.
// B staged in LDS per chunk (shared by all 4 waves); inner loop = imm-offset ds_reads.
__global__ void __launch_bounds__(256) k_scan1(const float* __restrict__ delta,
    const float* __restrict__ u, const float* __restrict__ xdbl,
    const float* __restrict__ alog, float* __restrict__ hfin, float* __restrict__ aprod)
{
    __shared__ float Bs[64*64];
    int bid = blockIdx.x;
    int b = bid & 7;
    int i = bid >> 3;          // 0..447
    int g = i % 7;             // groups 0..6 (last group's state never needed)
    int dblk = i / 7;          // 0..63
    int wave = threadIdx.x >> 6, lane = threadIdx.x & 63;
    int d = dblk*4 + wave;
    int tok0 = b*LSEQ + g*GLEN;
    const float* dptr = delta + (size_t)tok0*DI + d;
    const float* uptr = u     + (size_t)tok0*DI + d;
    const float* xrow = xdbl  + (size_t)tok0*XDBL_LD;
    float Acoef = -__expf(alog[d*DSN + lane]) * 1.44269504f;
    float h = 0.f, cum = 0.f;
    const float* Bl = Bs + lane;

    for (int c=0;c<GLEN/64;++c){
        const float* xr = xrow + (size_t)(c*64)*XDBL_LD;
        #pragma unroll
        for (int j=0;j<4;++j){
            int idx = threadIdx.x + j*256;          // 0..1023
            int row = idx >> 4, seg = idx & 15;
            *(f4*)&Bs[row*64 + seg*4] = *(const f4*)(xr + (size_t)row*XDBL_LD + 8 + seg*4);
        }
        float dv = dptr[(size_t)(c*64+lane)*DI];
        float uv = uptr[(size_t)(c*64+lane)*DI];
        float duv = dv*uv;
        float cs = dv;
        #pragma unroll
        for (int off=32; off; off>>=1) cs += __shfl_xor(cs, off);
        cum += cs;
        __syncthreads();
        #pragma unroll
        for (int j=0;j<64;++j){
            float Bn = Bl[j*64];
            float sd  = rdlane(dv,  j);
            float sdu = rdlane(duv, j);
            h = fmaf(exp2f(Acoef*sd), h, sdu*Bn);
        }
        __syncthreads();
    }
    size_t idx = ((size_t)(b*DI + d)*GRP + g)*DSN + lane;
    hfin[idx]  = h;
    aprod[idx] = exp2f(Acoef*cum);
}

// ---------------- scan combine: chain group states (8 serial steps per (b,d)) ----------------
__global__ void __launch_bounds__(256) k_comb(const float* __restrict__ hfin,
    const float* __restrict__ aprod, float* __restrict__ hin)
{
    int bd = blockIdx.x*4 + (threadIdx.x>>6);
    int lane = threadIdx.x & 63;
    size_t base = (size_t)bd*GRP*DSN + lane;
    float h = 0.f;
    hin[base] = 0.f;
    #pragma unroll
    for (int g=0; g<GRP-1; ++g){
        float hf = hfin[base + (size_t)g*DSN];
        float ap = aprod[base + (size_t)g*DSN];
        h = fmaf(ap, h, hf);
        hin[base + (size_t)(g+1)*DSN] = h;
    }
}

// ---------------- scan pass 2: full scan per group + gating, writes ygT ----------------
// grid: 4096 blocks; block = 4 waves = 4 consecutive d. B,C staged in LDS per chunk.
__global__ void __launch_bounds__(256) k_scan2(const float* __restrict__ delta,
    const float* __restrict__ u, const float* __restrict__ xz,
    const float* __restrict__ xdbl, const float* __restrict__ alog,
    const float* __restrict__ Dp, const float* __restrict__ hin,
    float* __restrict__ ygT)
{
    __shared__ float Bsh[64*64];
    __shared__ float Csh[64*64];
    __shared__ float Q[4][64][17];
    int bid = blockIdx.x;
    int b = bid & 7;
    int i = bid >> 3;          // 0..511
    int g = i & 7;
    int dblk = i >> 3;         // 0..63
    int wave = threadIdx.x >> 6, lane = threadIdx.x & 63;
    int d = dblk*4 + wave;
    int bd = b*DI + d;
    int tok0 = b*LSEQ + g*GLEN;
    float Acoef = -__expf(alog[d*DSN + lane]) * 1.44269504f;
    float Dd = Dp[d];
    float h = hin[((size_t)bd*GRP + g)*DSN + lane];
    const float* dptr = delta + (size_t)tok0*DI + d;
    const float* uptr = u     + (size_t)tok0*DI + d;
    const float* zptr = xz    + (size_t)tok0*2*DI + DI + d;
    const float* xrow = xdbl  + (size_t)tok0*XDBL_LD;
    float* yout = ygT + (size_t)bd*LSEQ + g*GLEN;
    float (*Qw)[17] = Q[wave];
    const int q16 = (lane>>4)*16;
    const int cidx = lane & 15;
    const float* Bl = Bsh + lane;
    const float* Cl = Csh + lane;

    for (int c=0;c<GLEN/64;++c){
        const float* xr = xrow + (size_t)(c*64)*XDBL_LD;
        #pragma unroll
        for (int j=0;j<4;++j){
            int idx = threadIdx.x + j*256;          // 0..1023
            int row = idx >> 4, seg = idx & 15;
            f4 vb = *(const f4*)(xr + (size_t)row*XDBL_LD + 8  + seg*4);
            f4 vc = *(const f4*)(xr + (size_t)row*XDBL_LD + 72 + seg*4);
            *(f4*)&Bsh[row*64 + seg*4] = vb;
            *(f4*)&Csh[row*64 + seg*4] = vc;
        }
        float dv = dptr[(size_t)(c*64+lane)*DI];
        float uv = uptr[(size_t)(c*64+lane)*DI];
        float zv = zptr[(size_t)(c*64+lane)*2*DI];
        float duv = dv*uv;
        __syncthreads();
        float y = 0.f;
        #pragma unroll
        for (int m=0;m<4;++m){
            #pragma unroll
            for (int k=0;k<16;++k){
                const int j = m*16+k;
                float Bn = Bl[j*64];
                float Cn = Cl[j*64];
                float sd  = rdlane(dv,  j);
                float sdu = rdlane(duv, j);
                float a = exp2f(Acoef*sd);
                h = fmaf(a, h, sdu*Bn);
                Qw[lane][k] = h*Cn;
            }
            // column-sum of 16-step micro-tile: 4 lanes per column, then 2 butterflies
            float r = 0.f;
            #pragma unroll
            for (int ii=0;ii<16;++ii) r += Qw[q16+ii][cidx];
            r += __shfl_xor(r, 16);
            r += __shfl_xor(r, 32);
            y = ((lane>>4)==m) ? r : y;
        }
        float yfull = fmaf(uv, Dd, y);
        float yg = yfull * zv * sigmoidf_(zv);
        yout[c*64 + lane] = yg;
        __syncthreads();
    }
}

extern "C" void kernel_launch(void* const* d_in, const int* in_sizes, int n_in,
                              void* d_out, int out_size, void* d_ws, size_t ws_size,
                              hipStream_t stream)
{
    (void)in_sizes; (void)n_in; (void)out_size; (void)ws_size;
    const float* x    = (const float*)d_in[0];
    const float* nw   = (const float*)d_in[1];
    const float* nb   = (const float*)d_in[2];
    const float* w_in = (const float*)d_in[3];
    const float* cw   = (const float*)d_in[4];
    const float* cb   = (const float*)d_in[5];
    const float* wx   = (const float*)d_in[6];
    const float* wdt  = (const float*)d_in[7];
    const float* bdt  = (const float*)d_in[8];
    const float* alog = (const float*)d_in[9];
    const float* Dp   = (const float*)d_in[10];
    const float* wo   = (const float*)d_in[11];
    float* out = (float*)d_out;

    float* ws    = (float*)d_ws;
    float* xz    = ws;                                  // NTOK*512
    float* u     = xz    + (size_t)NTOK*2*DI;           // NTOK*256
    float* xdbl  = u     + (size_t)NTOK*DI;             // NTOK*136 (+slack below)
    float* delta = xdbl  + (size_t)NTOK*XDBL_LD + 4096; // slack
    float* ygT   = delta + (size_t)NTOK*DI;             // NTOK*256
    float* stats = ygT   + (size_t)NTOK*DI;             // NTOK*2
    float* hfin  = stats + (size_t)NTOK*2;              // 2048*8*64
    float* aprod = hfin  + (size_t)NB*DI*GRP*DSN;
    float* hin   = aprod + (size_t)NB*DI*GRP*DSN;

    k_lnstats<<<NTOK/4, 256, 0, stream>>>(x, stats);

    dim3 g1(NTOK/64, 8);
    k_gemm<512,128,0><<<g1, 256, 0, stream>>>(x, w_in, xz, 512, stats, nw, nb, nullptr);

    k_conv<<<NTOK*64/256, 256, 0, stream>>>(xz, cw, cb, u);

    dim3 g2(NTOK/64, 3);
    k_gemm<136,256,1><<<g2, 256, 0, stream>>>(u, wx, xdbl, XDBL_LD, nullptr, nullptr, nullptr, nullptr);

    k_delta<<<NTOK/16, 256, 0, stream>>>(xdbl, wdt, bdt, delta);

    k_scan1<<<NB*(GRP-1)*64, 256, 0, stream>>>(delta, u, xdbl, alog, hfin, aprod);
    k_comb<<<NB*DI/4, 256, 0, stream>>>(hfin, aprod, hin);
    k_scan2<<<NB*GRP*64, 256, 0, stream>>>(delta, u, xz, xdbl, alog, Dp, hin, ygT);

    dim3 g3(NTOK/64, 2);
    k_gemm<128,256,2><<<g3, 256, 0, stream>>>(ygT, wo, out, 128, nullptr, nullptr, nullptr, x);
}

// Round 4
// 584.071 us; speedup vs baseline: 1.1178x; 1.1178x over previous
//
#include <hip/hip_runtime.h>
#include <math.h>

#define DM 128
#define DI 256
#define DSN 64
#define NB 8
#define LSEQ 4096
#define NTOK (NB*LSEQ)
#define XDBL_LD 136
#define GRP 8
#define GLEN (LSEQ/GRP)   // 512

typedef float4 f4;
typedef __attribute__((ext_vector_type(8))) short bf16x8;
typedef __attribute__((ext_vector_type(4))) float f32x4;
typedef __attribute__((ext_vector_type(8))) unsigned short us8;

__device__ __forceinline__ float sigmoidf_(float x){ return 1.f/(1.f+__expf(-x)); }
__device__ __forceinline__ unsigned short f2bf(float f){
    unsigned u = __float_as_uint(f);
    unsigned r = u + 0x7FFFu + ((u>>16)&1u);   // RNE
    return (unsigned short)(r>>16);
}

// ---------------- LayerNorm stats (mu, rstd) per token ----------------
__global__ void __launch_bounds__(256) k_lnstats(const float* __restrict__ x, float* __restrict__ stats){
    int tok = blockIdx.x*4 + (threadIdx.x>>6);
    int lane = threadIdx.x & 63;
    const float* row = x + (size_t)tok*DM;
    float a = row[lane], b = row[lane+64];
    float s = a+b, ss = a*a+b*b;
    #pragma unroll
    for (int off=32; off>0; off>>=1){ s += __shfl_xor(s,off); ss += __shfl_xor(ss,off); }
    if (lane==0){
        float mu = s*(1.f/128.f);
        float var = ss*(1.f/128.f) - mu*mu;
        stats[tok*2+0] = mu;
        stats[tok*2+1] = rsqrtf(var + 1e-6f);
    }
}

// ---------------- bf16 MFMA GEMM: C[M][N] = A[M][K] * Bw[N][K]^T ----------------
// MODE 0: A = LN(x) fp32->bf16 on the fly (in_proj)
// MODE 1: A = fp32 row-major (x_proj, A=u), N=136 guarded
// MODE 2: A = bf16 row-major (out_proj, A=ygbf) + residual
// tile 128(M) x 64(N), BK=64, 4 waves (2Mx2N), each wave 64x32 = 4x2 16x16 frags
template<int N_DIM,int K_DIM,int MODE>
__global__ void __launch_bounds__(256) k_gemm_bf(const float* __restrict__ Af32,
    const unsigned short* __restrict__ Abf, const float* __restrict__ Bw,
    float* __restrict__ Cout, int ldC,
    const float* __restrict__ stats, const float* __restrict__ nw,
    const float* __restrict__ nb, const float* __restrict__ resid)
{
    __shared__ unsigned short Abuf[128*72];   // stride 72 bf16 = 144B rows (16B aligned)
    __shared__ unsigned short Bbuf[64*72];
    const int tid = threadIdx.x;
    const int m0 = blockIdx.x*128;
    const int n0 = blockIdx.y*64;
    const int wave = tid>>6, lane = tid&63;
    const int wm = wave>>1, wn = wave&1;
    const int lr = lane&15, lk = (lane>>4)*8;
    f32x4 acc[4][2];
    #pragma unroll
    for (int i=0;i<4;++i){
        #pragma unroll
        for (int j=0;j<2;++j) acc[i][j] = (f32x4){0.f,0.f,0.f,0.f};
    }

    for (int k0=0; k0<K_DIM; k0+=64){
        // ---- stage A: 128 x 64 ----
        {
            int row = tid>>1, ks = (tid&1)*32;
            int m = m0 + row;
            unsigned short* dst = &Abuf[row*72 + ks];
            if (MODE==2){
                const unsigned short* src = Abf + (size_t)m*K_DIM + k0 + ks;
                #pragma unroll
                for (int q=0;q<4;++q) *(us8*)(dst+q*8) = *(const us8*)(src+q*8);
            } else {
                const float* src = Af32 + (size_t)m*K_DIM + k0 + ks;
                float mu=0.f, rs=1.f;
                if (MODE==0){ mu = stats[2*m]; rs = stats[2*m+1]; }
                #pragma unroll
                for (int q=0;q<4;++q){
                    f4 v0 = *(const f4*)(src+q*8);
                    f4 v1 = *(const f4*)(src+q*8+4);
                    if (MODE==0){
                        int kk = k0+ks+q*8;
                        f4 w0=*(const f4*)(nw+kk), w1=*(const f4*)(nw+kk+4);
                        f4 c0=*(const f4*)(nb+kk), c1=*(const f4*)(nb+kk+4);
                        v0.x=(v0.x-mu)*rs*w0.x+c0.x; v0.y=(v0.y-mu)*rs*w0.y+c0.y;
                        v0.z=(v0.z-mu)*rs*w0.z+c0.z; v0.w=(v0.w-mu)*rs*w0.w+c0.w;
                        v1.x=(v1.x-mu)*rs*w1.x+c1.x; v1.y=(v1.y-mu)*rs*w1.y+c1.y;
                        v1.z=(v1.z-mu)*rs*w1.z+c1.z; v1.w=(v1.w-mu)*rs*w1.w+c1.w;
                    }
                    us8 o = {f2bf(v0.x),f2bf(v0.y),f2bf(v0.z),f2bf(v0.w),
                             f2bf(v1.x),f2bf(v1.y),f2bf(v1.z),f2bf(v1.w)};
                    *(us8*)(dst+q*8) = o;
                }
            }
        }
        // ---- stage B (weights): 64 x 64 ----
        {
            int row = tid>>2, ks = (tid&3)*16;
            int n = n0 + row;
            unsigned short* dst = &Bbuf[row*72 + ks];
            #pragma unroll
            for (int q=0;q<2;++q){
                f4 v0={0.f,0.f,0.f,0.f}, v1={0.f,0.f,0.f,0.f};
                if (N_DIM%64==0 || n < N_DIM){
                    const float* src = Bw + (size_t)n*K_DIM + k0 + ks + q*8;
                    v0 = *(const f4*)src; v1 = *(const f4*)(src+4);
                }
                us8 o = {f2bf(v0.x),f2bf(v0.y),f2bf(v0.z),f2bf(v0.w),
                         f2bf(v1.x),f2bf(v1.y),f2bf(v1.z),f2bf(v1.w)};
                *(us8*)(dst+q*8) = o;
            }
        }
        __syncthreads();
        #pragma unroll
        for (int kk=0; kk<64; kk+=32){
            bf16x8 bfr[2], afr[4];
            #pragma unroll
            for (int fn=0;fn<2;++fn)
                bfr[fn] = *(const bf16x8*)&Bbuf[(wn*32+fn*16+lr)*72 + kk + lk];
            #pragma unroll
            for (int fm=0;fm<4;++fm)
                afr[fm] = *(const bf16x8*)&Abuf[(wm*64+fm*16+lr)*72 + kk + lk];
            #pragma unroll
            for (int fm=0;fm<4;++fm){
                #pragma unroll
                for (int fn=0;fn<2;++fn)
                    acc[fm][fn] = __builtin_amdgcn_mfma_f32_16x16x32_bf16(afr[fm], bfr[fn], acc[fm][fn], 0,0,0);
            }
        }
        __syncthreads();
    }
    // ---- epilogue: C/D layout col=lane&15, row=(lane>>4)*4+reg ----
    const int cb = (lane>>4)*4;
    #pragma unroll
    for (int fm=0;fm<4;++fm){
        #pragma unroll
        for (int fn=0;fn<2;++fn){
            int col = n0 + wn*32 + fn*16 + lr;
            if (N_DIM%64!=0 && col >= N_DIM) continue;
            #pragma unroll
            for (int r=0;r<4;++r){
                int m = m0 + wm*64 + fm*16 + cb + r;
                float v = acc[fm][fn][r];
                if (MODE==2) v += resid[(size_t)m*N_DIM + col];
                Cout[(size_t)m*ldC + col] = v;
            }
        }
    }
}

// ---------------- transpose ygT fp32 [b*DI+d][t] -> ygbf bf16 [b*L+t][d] ----------------
__global__ void __launch_bounds__(256) k_trans(const float* __restrict__ ygT,
    unsigned short* __restrict__ ygbf)
{
    __shared__ float T[64][65];
    int t0 = blockIdx.x*64;
    int w  = blockIdx.y;           // 0..31
    int b  = w>>2, d0 = (w&3)*64;
    int tid = threadIdx.x;
    {
        int dl = tid>>2, ts = (tid&3)*16;
        const float* src = ygT + ((size_t)(b*DI + d0 + dl))*LSEQ + t0 + ts;
        #pragma unroll
        for (int q=0;q<4;++q) *(f4*)&T[dl][ts+q*4] = *(const f4*)(src+q*4);
    }
    __syncthreads();
    {
        int tl = tid>>2, ds8 = (tid&3)*16;
        unsigned short* dst = ygbf + ((size_t)(b*LSEQ + t0 + tl))*DI + d0 + ds8;
        us8 o0, o1;
        #pragma unroll
        for (int j=0;j<8;++j){ o0[j]=f2bf(T[ds8+j][tl]); o1[j]=f2bf(T[ds8+8+j][tl]); }
        *(us8*)dst = o0; *(us8*)(dst+8) = o1;
    }
}

// ---------------- causal depthwise conv (k=4) + SiLU ----------------
__global__ void __launch_bounds__(256) k_conv(const float* __restrict__ xz,
    const float* __restrict__ cw, const float* __restrict__ cb, float* __restrict__ u)
{
    int idx = blockIdx.x*256 + threadIdx.x;
    int dq = idx & 63;
    int tok = idx >> 6;
    int t = tok & (LSEQ-1);
    f4 w0 = *(const f4*)(cw + (dq*4+0)*4);
    f4 w1 = *(const f4*)(cw + (dq*4+1)*4);
    f4 w2 = *(const f4*)(cw + (dq*4+2)*4);
    f4 w3 = *(const f4*)(cw + (dq*4+3)*4);
    f4 r  = *(const f4*)(cb + dq*4);
    #pragma unroll
    for (int j=0;j<4;++j){
        int tj = t-3+j;
        if (tj < 0) continue;
        f4 v = *(const f4*)(xz + (size_t)(tok-3+j)*(2*DI) + dq*4);
        r.x = fmaf(v.x, ((const float*)&w0)[j], r.x);
        r.y = fmaf(v.y, ((const float*)&w1)[j], r.y);
        r.z = fmaf(v.z, ((const float*)&w2)[j], r.z);
        r.w = fmaf(v.w, ((const float*)&w3)[j], r.w);
    }
    r.x *= sigmoidf_(r.x); r.y *= sigmoidf_(r.y);
    r.z *= sigmoidf_(r.z); r.w *= sigmoidf_(r.w);
    *(f4*)(u + (size_t)tok*DI + dq*4) = r;
}

// ---------------- delta = softplus(dt @ Wdt^T + bdt) ----------------
__global__ void __launch_bounds__(256) k_delta(const float* __restrict__ xdbl,
    const float* __restrict__ Wdt, const float* __restrict__ bdt, float* __restrict__ delta)
{
    int d = threadIdx.x;
    int tok0 = blockIdx.x * 16;
    f4 w0 = *(const f4*)(Wdt + d*8);
    f4 w1 = *(const f4*)(Wdt + d*8 + 4);
    float bias = bdt[d];
    __shared__ float dts[16][8];
    if (threadIdx.x < 128){
        int ti = threadIdx.x >> 3, r = threadIdx.x & 7;
        dts[ti][r] = xdbl[(size_t)(tok0+ti)*XDBL_LD + r];
    }
    __syncthreads();
    #pragma unroll 4
    for (int ti=0; ti<16; ++ti){
        f4 d0 = *(const f4*)&dts[ti][0];
        f4 d1 = *(const f4*)&dts[ti][4];
        float v = bias;
        v = fmaf(d0.x,w0.x, v); v = fmaf(d0.y,w0.y, v);
        v = fmaf(d0.z,w0.z, v); v = fmaf(d0.w,w0.w, v);
        v = fmaf(d1.x,w1.x, v); v = fmaf(d1.y,w1.y, v);
        v = fmaf(d1.z,w1.z, v); v = fmaf(d1.w,w1.w, v);
        float sp = (v > 20.f) ? v : log1pf(__expf(v));
        delta[(size_t)(tok0+ti)*DI + d] = sp;
    }
}

// ---------------- scan pass 1 (R2 version): per-group (decay product, final state) ----------------
__global__ void __launch_bounds__(256,8) k_scan1(const float* __restrict__ delta,
    const float* __restrict__ u, const float* __restrict__ xdbl,
    const float* __restrict__ alog, float* __restrict__ hfin, float* __restrict__ aprod)
{
    int bid = blockIdx.x;
    int b = bid & 7;
    int i = bid >> 3;
    int g = i % 7;
    int dblk = i / 7;
    int wave = threadIdx.x >> 6, lane = threadIdx.x & 63;
    int d = dblk*4 + wave;
    int tok0 = b*LSEQ + g*GLEN;
    const float* dptr = delta + (size_t)tok0*DI + d;
    const float* uptr = u     + (size_t)tok0*DI + d;
    const float* xrow = xdbl  + (size_t)tok0*XDBL_LD;
    float Acoef = -__expf(alog[d*DSN + lane]) * 1.44269504f;
    float h = 0.f, cum = 0.f;
    float Bpf[8];
    #pragma unroll
    for (int k=0;k<8;++k) Bpf[k] = xrow[(size_t)k*XDBL_LD + 8 + lane];
    const float* pf = xrow + (size_t)8*XDBL_LD;
    for (int c=0;c<GLEN/64;++c){
        float dv = dptr[(size_t)(c*64+lane)*DI];
        float uv = uptr[(size_t)(c*64+lane)*DI];
        float duv = dv*uv;
        float cs = dv;
        #pragma unroll
        for (int off=32; off; off>>=1) cs += __shfl_xor(cs, off);
        cum += cs;
        #pragma unroll 1
        for (int jj=0;jj<8;++jj){
            #pragma unroll
            for (int k=0;k<8;++k){
                int j = jj*8+k;
                float Bn = Bpf[k];
                Bpf[k] = pf[8+lane];
                pf += XDBL_LD;
                float sd  = __int_as_float(__builtin_amdgcn_readlane(__float_as_int(dv),  j));
                float sdu = __int_as_float(__builtin_amdgcn_readlane(__float_as_int(duv), j));
                float a = exp2f(Acoef*sd);
                h = fmaf(a, h, sdu*Bn);
            }
        }
    }
    size_t idx = ((size_t)(b*DI + d)*GRP + g)*DSN + lane;
    hfin[idx]  = h;
    aprod[idx] = exp2f(Acoef*cum);
}

// ---------------- scan combine ----------------
__global__ void __launch_bounds__(256) k_comb(const float* __restrict__ hfin,
    const float* __restrict__ aprod, float* __restrict__ hin)
{
    int bd = blockIdx.x*4 + (threadIdx.x>>6);
    int lane = threadIdx.x & 63;
    size_t base = (size_t)bd*GRP*DSN + lane;
    float h = 0.f;
    hin[base] = 0.f;
    #pragma unroll
    for (int g=0; g<GRP-1; ++g){
        float hf = hfin[base + (size_t)g*DSN];
        float ap = aprod[base + (size_t)g*DSN];
        h = fmaf(ap, h, hf);
        hin[base + (size_t)(g+1)*DSN] = h;
    }
}

// ---------------- scan pass 2 (R2 version): full scan per group + gating ----------------
__global__ void __launch_bounds__(256,7) k_scan2(const float* __restrict__ delta,
    const float* __restrict__ u, const float* __restrict__ xz,
    const float* __restrict__ xdbl, const float* __restrict__ alog,
    const float* __restrict__ Dp, const float* __restrict__ hin,
    float* __restrict__ ygT)
{
    __shared__ float Q[4][64][17];
    int bid = blockIdx.x;
    int b = bid & 7;
    int i = bid >> 3;
    int g = i & 7;
    int dblk = i >> 3;
    int wave = threadIdx.x >> 6, lane = threadIdx.x & 63;
    int d = dblk*4 + wave;
    int bd = b*DI + d;
    int tok0 = b*LSEQ + g*GLEN;
    float Acoef = -__expf(alog[d*DSN + lane]) * 1.44269504f;
    float Dd = Dp[d];
    float h = hin[((size_t)bd*GRP + g)*DSN + lane];
    const float* dptr = delta + (size_t)tok0*DI + d;
    const float* uptr = u     + (size_t)tok0*DI + d;
    const float* zptr = xz    + (size_t)tok0*2*DI + DI + d;
    const float* xrow = xdbl  + (size_t)tok0*XDBL_LD;
    float* yout = ygT + (size_t)bd*LSEQ + g*GLEN;
    float Bpf[8], Cpf[8];
    #pragma unroll
    for (int k=0;k<8;++k){
        Bpf[k] = xrow[(size_t)k*XDBL_LD + 8 + lane];
        Cpf[k] = xrow[(size_t)k*XDBL_LD + 72 + lane];
    }
    const float* pf = xrow + (size_t)8*XDBL_LD;
    float (*Qw)[17] = Q[wave];
    int q16 = (lane>>4)*16;
    int cidx = lane & 15;
    for (int c=0;c<GLEN/64;++c){
        float dv = dptr[(size_t)(c*64+lane)*DI];
        float uv = uptr[(size_t)(c*64+lane)*DI];
        float zv = zptr[(size_t)(c*64+lane)*2*DI];
        float duv = dv*uv;
        float y = 0.f;
        #pragma unroll 1
        for (int m=0;m<4;++m){
            #pragma unroll
            for (int k=0;k<16;++k){
                int slot = k&7;
                float Bn = Bpf[slot], Cn = Cpf[slot];
                Bpf[slot] = pf[8+lane];
                Cpf[slot] = pf[72+lane];
                pf += XDBL_LD;
                int j = m*16+k;
                float sd  = __int_as_float(__builtin_amdgcn_readlane(__float_as_int(dv),  j));
                float sdu = __int_as_float(__builtin_amdgcn_readlane(__float_as_int(duv), j));
                float a = exp2f(Acoef*sd);
                h = fmaf(a, h, sdu*Bn);
                Qw[lane][k] = h*Cn;
            }
            float r = 0.f;
            #pragma unroll
            for (int ii=0;ii<16;++ii) r += Qw[q16+ii][cidx];
            r += __shfl_xor(r, 16);
            r += __shfl_xor(r, 32);
            y = ((lane>>4)==m) ? r : y;
        }
        float yfull = fmaf(uv, Dd, y);
        float yg = yfull * zv * sigmoidf_(zv);
        yout[c*64 + lane] = yg;
    }
}

extern "C" void kernel_launch(void* const* d_in, const int* in_sizes, int n_in,
                              void* d_out, int out_size, void* d_ws, size_t ws_size,
                              hipStream_t stream)
{
    (void)in_sizes; (void)n_in; (void)out_size; (void)ws_size;
    const float* x    = (const float*)d_in[0];
    const float* nw   = (const float*)d_in[1];
    const float* nb   = (const float*)d_in[2];
    const float* w_in = (const float*)d_in[3];
    const float* cw   = (const float*)d_in[4];
    const float* cb   = (const float*)d_in[5];
    const float* wx   = (const float*)d_in[6];
    const float* wdt  = (const float*)d_in[7];
    const float* bdt  = (const float*)d_in[8];
    const float* alog = (const float*)d_in[9];
    const float* Dp   = (const float*)d_in[10];
    const float* wo   = (const float*)d_in[11];
    float* out = (float*)d_out;

    float* ws    = (float*)d_ws;
    float* xz    = ws;                                  // NTOK*512
    float* u     = xz    + (size_t)NTOK*2*DI;           // NTOK*256
    float* xdbl  = u     + (size_t)NTOK*DI;             // NTOK*136 (+slack)
    float* delta = xdbl  + (size_t)NTOK*XDBL_LD + 4096; // slack for prefetch over-read
    float* ygT   = delta + (size_t)NTOK*DI;             // NTOK*256
    float* stats = ygT   + (size_t)NTOK*DI;             // NTOK*2
    float* hfin  = stats + (size_t)NTOK*2;
    float* aprod = hfin  + (size_t)NB*DI*GRP*DSN;
    float* hin   = aprod + (size_t)NB*DI*GRP*DSN;
    unsigned short* ygbf = (unsigned short*)(hin + (size_t)NB*DI*GRP*DSN); // NTOK*256 bf16

    k_lnstats<<<NTOK/4, 256, 0, stream>>>(x, stats);

    dim3 g1(NTOK/128, 512/64);
    k_gemm_bf<512,128,0><<<g1, 256, 0, stream>>>(x, nullptr, w_in, xz, 512, stats, nw, nb, nullptr);

    k_conv<<<NTOK*64/256, 256, 0, stream>>>(xz, cw, cb, u);

    dim3 g2(NTOK/128, 3);
    k_gemm_bf<136,256,1><<<g2, 256, 0, stream>>>(u, nullptr, wx, xdbl, XDBL_LD, nullptr, nullptr, nullptr, nullptr);

    k_delta<<<NTOK/16, 256, 0, stream>>>(xdbl, wdt, bdt, delta);

    k_scan1<<<NB*(GRP-1)*64, 256, 0, stream>>>(delta, u, xdbl, alog, hfin, aprod);
    k_comb<<<NB*DI/4, 256, 0, stream>>>(hfin, aprod, hin);
    k_scan2<<<NB*GRP*64, 256, 0, stream>>>(delta, u, xz, xdbl, alog, Dp, hin, ygT);

    dim3 gt(LSEQ/64, NB*4);
    k_trans<<<gt, 256, 0, stream>>>(ygT, ygbf);

    dim3 g3(NTOK/128, 2);
    k_gemm_bf<128,256,2><<<g3, 256, 0, stream>>>(nullptr, ygbf, wo, out, 128, nullptr, nullptr, nullptr, x);
}